// Round 4
// baseline (120.192 us; speedup 1.0000x reference)
//
#include <hip/hip_runtime.h>
#include <math.h>

// ---------------------------------------------------------------------------
// HybridQuantumDQN: encoder MLP -> 8-qubit statevector sim -> decoder MLP.
// R14: R13 + amdgpu_waves_per_eu(1,2) (allocator budget 256 VGPR instead of
//      the 128 it self-capped to — grid only supplies 2 waves/SIMD, so the
//      4-wave budget was unreachable and only cost scheduling slack), and
//      per-layer gate-coeff float4s prefetched into registers (16 lgkm-wait
//      points per layer removed; affordable under the relaxed budget).
// R13: TWO samples per 8-lane group (ILP doubling). zA[32]+zB[32] v2f state,
//      every gate applied to A and B interleaved. Weight rows loaded once.
//      2048 blocks x 64 thr.
// R12: 1-wave blocks, no __syncthreads (wave_barrier ordering only).
// R11: final RY layer removed — observables rotated: out_w = cosT*<Z_w> -
//      sinT*<X_w>; <X_w> via packed-fma correlators. Scalar-coeff VOP3P
//      broadcast via op_sel_hi[0]=0 (no v_mov).
// Base (R7): 8 lanes/sample on lane bits {0,1,3} -> cross-wire exchanges all
// DPP (xor1/xor2 = quad_perm, xor8 = row_ror:8). amp = (G<<5)|t. Wires 0..2
// cross, 3..7 in-lane. Layer 0 = product state. CZ = closed-form diagonal.
//
// Session conclusions (measured): ~55us kernel flat across -8% inst (R11),
// TLP restructure (R12), ILP x2 (R13). VALUBusy ~70%, HBM 0.4%, 0 LDS
// conflicts. v_pk_* are half-rate (4cyc) -> pure-issue floor ~28us; the gap
// is per-wave stalls. R13's VGPR=128 (exact occupancy boundary) suggests
// allocator-squeezed scheduling — this round tests that.
// ---------------------------------------------------------------------------

#define PI_F 3.14159265358979323846f

typedef float v2f __attribute__((ext_vector_type(2)));

struct C2 { float re, im; };
__device__ __forceinline__ C2 cmul(C2 a, C2 b) {
    C2 r;
    r.re = fmaf(a.re, b.re, -a.im * b.im);
    r.im = fmaf(a.re, b.im,  a.im * b.re);
    return r;
}
__device__ __forceinline__ float fxor(float x, int m) {
    return __int_as_float(__float_as_int(x) ^ m);
}

// ---------------- packed fp32 primitives (VOP3P) ----------------
__device__ __forceinline__ v2f pk_fma(v2f a, v2f b, v2f c) {
    v2f d; asm("v_pk_fma_f32 %0, %1, %2, %3" : "=v"(d) : "v"(a), "v"(b), "v"(c)); return d;
}

// scalar-coefficient variants: coefficient lives in word0 of its VGPR pair;
// op_sel_hi[0]=0 makes BOTH result halves read word0 (free HW broadcast).
__device__ __forceinline__ v2f mkbc(float c) { v2f r; r.x = c; return r; }

__device__ __forceinline__ v2f pk_mul_s(float c, v2f z) {
    v2f cb = mkbc(c), d;
    asm("v_pk_mul_f32 %0, %1, %2 op_sel_hi:[0,1]"
        : "=v"(d) : "v"(cb), "v"(z));
    return d;
}
__device__ __forceinline__ v2f pk_mul_neg_s(float c, v2f z) {
    v2f cb = mkbc(c), d;
    asm("v_pk_mul_f32 %0, %1, %2 op_sel_hi:[0,1] neg_lo:[1,0] neg_hi:[1,0]"
        : "=v"(d) : "v"(cb), "v"(z));
    return d;
}
__device__ __forceinline__ v2f pk_fma_s(float c, v2f b, v2f acc) {
    v2f cb = mkbc(c), d;
    asm("v_pk_fma_f32 %0, %1, %2, %3 op_sel_hi:[0,1,1]"
        : "=v"(d) : "v"(cb), "v"(b), "v"(acc));
    return d;
}
// d = -(c*b) + acc
__device__ __forceinline__ v2f pk_fma_nn_s(float c, v2f b, v2f acc) {
    v2f cb = mkbc(c), d;
    asm("v_pk_fma_f32 %0, %1, %2, %3 op_sel_hi:[0,1,1] neg_lo:[1,0,0] neg_hi:[1,0,0]"
        : "=v"(d) : "v"(cb), "v"(b), "v"(acc));
    return d;
}
// d.lo = -c*z.hi + acc.lo ; d.hi = c*z.lo + acc.hi   (complex cross term)
__device__ __forceinline__ v2f pk_fma_swl_s(float c, v2f z, v2f acc) {
    v2f cb = mkbc(c), d;
    asm("v_pk_fma_f32 %0, %1, %2, %3 op_sel:[0,1,0] op_sel_hi:[0,0,1] neg_lo:[1,0,0]"
        : "=v"(d) : "v"(cb), "v"(z), "v"(acc));
    return d;
}
// d.lo = c*z.hi + acc.lo ; d.hi = -c*z.lo + acc.hi
__device__ __forceinline__ v2f pk_fma_swh_s(float c, v2f z, v2f acc) {
    v2f cb = mkbc(c), d;
    asm("v_pk_fma_f32 %0, %1, %2, %3 op_sel:[0,1,0] op_sel_hi:[0,0,1] neg_hi:[1,0,0]"
        : "=v"(d) : "v"(cb), "v"(z), "v"(acc));
    return d;
}
// z * (re + i*im), complex scalar coefficient
__device__ __forceinline__ v2f cmulv(v2f z, C2 c) {
    return pk_fma_swl_s(c.im, z, pk_mul_s(c.re, z));
}

// ---------------- cross-lane exchange (all DPP) ----------------
template<int CTRL>
__device__ __forceinline__ float dppf(float x) {
    int xi = __float_as_int(x);
    int r = __builtin_amdgcn_update_dpp(xi, xi, CTRL, 0xF, 0xF, false);
    return __int_as_float(r);
}
template<int M>
__device__ __forceinline__ float lxor(float x) {
    if constexpr (M == 1)      return dppf<0xB1>(x);   // quad_perm [1,0,3,2]
    else if constexpr (M == 2) return dppf<0x4E>(x);   // quad_perm [2,3,0,1]
    else                       return dppf<0x128>(x);  // row_ror:8 == lane^8 in row16
}

// ---------------- gates ----------------
// fused SU(2) gate G = Rot * RY from a preloaded coeff float4:
// columns (a,b); G = [[a,-conj(b)],[b,conj(a)]]
__device__ __forceinline__ void make_G2(float4 c0, float cc, float ss,
                                        float& ar, float& ai, float& br, float& bi) {
    ar = fmaf(c0.x, cc, -c0.z * ss);
    ai = fmaf(c0.y, cc,  c0.w * ss);
    br = fmaf(c0.z, cc,  c0.x * ss);
    bi = fmaf(c0.w, cc, -c0.y * ss);
}

// cross-lane SU(2) on BOTH samples, chunk-interleaved: gather A, gather B
// (32 DPP), then 32 pk for A and 32 pk for B — B fills A's latency.
template<int M>
__device__ __forceinline__ void su2_cross2(
        float cSrA, float cSiA, float cOrA, float cOiA,
        float cSrB, float cSiB, float cOrB, float cOiB,
        v2f zA[32], v2f zB[32]) {
#pragma unroll
    for (int c = 0; c < 4; c++) {
        v2f pA[8], pB[8];
#pragma unroll
        for (int k = 0; k < 8; k++) {
            pA[k].x = lxor<M>(zA[c * 8 + k].x);
            pA[k].y = lxor<M>(zA[c * 8 + k].y);
        }
#pragma unroll
        for (int k = 0; k < 8; k++) {
            pB[k].x = lxor<M>(zB[c * 8 + k].x);
            pB[k].y = lxor<M>(zB[c * 8 + k].y);
        }
#pragma unroll
        for (int k = 0; k < 8; k++) {
            const int t = c * 8 + k;
            v2f n = pk_mul_s(cSrA, zA[t]);
            n = pk_fma_swl_s(cSiA, zA[t], n);
            n = pk_fma_s    (cOrA, pA[k], n);
            n = pk_fma_swl_s(cOiA, pA[k], n);
            zA[t] = n;
            v2f m = pk_mul_s(cSrB, zB[t]);
            m = pk_fma_swl_s(cSiB, zB[t], m);
            m = pk_fma_s    (cOrB, pB[k], m);
            m = pk_fma_swl_s(cOiB, pB[k], m);
            zB[t] = m;
        }
    }
}

// in-lane SU(2) on reg-index bit ST, both samples per iteration
template<int ST>
__device__ __forceinline__ void su2_inlane2(
        float arA, float aiA, float brA, float biA,
        float arB, float aiB, float brB, float biB,
        v2f zA[32], v2f zB[32]) {
#pragma unroll
    for (int t = 0; t < 32; t++) {
        if ((t & ST) == 0) {
            const int u = t + ST;
            {
                v2f x = zA[t], y = zA[u];
                v2f nx = pk_mul_s(arA, x);
                nx = pk_fma_swl_s(aiA, x, nx);
                nx = pk_fma_nn_s (brA, y, nx);
                nx = pk_fma_swl_s(biA, y, nx);
                v2f ny = pk_mul_s(brA, x);
                ny = pk_fma_swl_s(biA, x, ny);
                ny = pk_fma_s    (arA, y, ny);
                ny = pk_fma_swh_s(aiA, y, ny);
                zA[t] = nx; zA[u] = ny;
            }
            {
                v2f x = zB[t], y = zB[u];
                v2f nx = pk_mul_s(arB, x);
                nx = pk_fma_swl_s(aiB, x, nx);
                nx = pk_fma_nn_s (brB, y, nx);
                nx = pk_fma_swl_s(biB, y, nx);
                v2f ny = pk_mul_s(brB, x);
                ny = pk_fma_swl_s(biB, x, ny);
                ny = pk_fma_s    (arB, y, ny);
                ny = pk_fma_swh_s(aiB, y, ny);
                zB[t] = nx; zB[u] = ny;
            }
        }
    }
}

// ---------------- X correlators: <X_w> = sum_k Re(conj(z_k) z_{k^w}) --------
template<int M>
__device__ __forceinline__ v2f xcorr_cross(const v2f z[32]) {
    v2f acc = (v2f){0.0f, 0.0f};
#pragma unroll
    for (int c = 0; c < 4; c++) {
        v2f p[8];
#pragma unroll
        for (int k = 0; k < 8; k++) {
            p[k].x = lxor<M>(z[c * 8 + k].x);
            p[k].y = lxor<M>(z[c * 8 + k].y);
        }
#pragma unroll
        for (int k = 0; k < 8; k++) acc = pk_fma(z[c * 8 + k], p[k], acc);
    }
    return acc;
}
template<int ST>
__device__ __forceinline__ v2f xcorr_inlane(const v2f z[32]) {
    v2f acc = (v2f){0.0f, 0.0f};
#pragma unroll
    for (int t = 0; t < 32; t++)
        if ((t & ST) == 0) acc = pk_fma(z[t], z[t + ST], acc);
    return acc;
}

// CZ t-part (5-bit): parity of adjacent-bit ANDs
__host__ __device__ constexpr bool czt5(int t) {
    return ((((t >> 4) & (t >> 3)) ^ ((t >> 3) & (t >> 2)) ^
             ((t >> 2) & (t >> 1)) ^ ((t >> 1) & t)) & 1) != 0;
}

// Z-readout tree: probs -> zW[8] partials for one sample
__device__ __forceinline__ void z_readout(const v2f z[32], int g0b, int g1b, int g2b,
                                          float zW[8]) {
    float p[32];
#pragma unroll
    for (int t = 0; t < 32; t++) p[t] = fmaf(z[t].x, z[t].x, z[t].y * z[t].y);
    float s16[16];
    float d = 0.0f;
#pragma unroll
    for (int i = 0; i < 16; i++) {
        s16[i] = p[2*i] + p[2*i+1];
        d += p[2*i] - p[2*i+1];
    }
    zW[7] = d;
    float s8[8]; d = 0.0f;
#pragma unroll
    for (int i = 0; i < 8; i++) {
        s8[i] = s16[2*i] + s16[2*i+1];
        d += s16[2*i] - s16[2*i+1];
    }
    zW[6] = d;
    float s4[4]; d = 0.0f;
#pragma unroll
    for (int i = 0; i < 4; i++) {
        s4[i] = s8[2*i] + s8[2*i+1];
        d += s8[2*i] - s8[2*i+1];
    }
    zW[5] = d;
    float s2a = s4[0] + s4[1], s2b = s4[2] + s4[3];
    zW[4] = (s4[0] - s4[1]) + (s4[2] - s4[3]);
    float sumP = s2a + s2b;
    zW[3] = s2a - s2b;
    zW[0] = g2b ? -sumP : sumP;
    zW[1] = g1b ? -sumP : sumP;
    zW[2] = g0b ? -sumP : sumP;
}

__global__ __launch_bounds__(64)
__attribute__((amdgpu_waves_per_eu(1, 2)))
void qdqn_kernel(
    const float* __restrict__ x,
    const float* __restrict__ ew1, const float* __restrict__ eb1,
    const float* __restrict__ ew2, const float* __restrict__ eb2,
    const float* __restrict__ qw,
    const float* __restrict__ dw1, const float* __restrict__ db1,
    const float* __restrict__ dw2, const float* __restrict__ db2,
    float* __restrict__ out, int B, int NL) {
    // one wave per block; all LDS exchange is wave-internal (in-order LDS),
    // ordered with wave_barrier only.
    __shared__ __align__(16) float c_lds[32 * 4];
    __shared__ __align__(16) float hx[16][8];     // h / h2 exchange (A:0-7 B:8-15)
    __shared__ __align__(16) float csx[16][16];   // (c,s) exchange

    const int lane = threadIdx.x;   // blockDim.x == 64
    // sample lane bits {0,1,3}; group id bits {2,4,5} -> all-DPP cross wires
    const int g = (lane & 3) | ((lane >> 1) & 4);          // amp bits 7..5
    const int grp = ((lane >> 2) & 1) | ((lane >> 3) & 6); // group in wave
    int sA = blockIdx.x * 16 + grp;
    int sB = sA + 8;
    if (sA >= B) sA = B - 1;
    if (sB >= B) sB = B - 1;

    // ---- prefetch x for both samples early ----
    float xvA[16], xvB[16];
    {
        const float4* xpA = (const float4*)(x + sA * 16);
        const float4* xpB = (const float4*)(x + sB * 16);
#pragma unroll
        for (int i = 0; i < 4; i++) {
            float4 a = xpA[i], b = xpB[i];
            xvA[4*i] = a.x; xvA[4*i+1] = a.y; xvA[4*i+2] = a.z; xvA[4*i+3] = a.w;
            xvB[4*i] = b.x; xvB[4*i+1] = b.y; xvB[4*i+2] = b.z; xvB[4*i+3] = b.w;
        }
    }

    // ---- Rot SU(2) coeffs once per wave: a = e^{-iA}c, b = e^{-iB}s ----
    const int n_gates = NL * 8;   // 32 <= 64
    if (lane < n_gates) {
        const int gg = lane;
        float phi = qw[3 * gg + 0], th = qw[3 * gg + 1], om = qw[3 * gg + 2];
        float c = __cosf(0.5f * th), sv = __sinf(0.5f * th);
        float A = 0.5f * (phi + om), Bb = 0.5f * (phi - om);
        float* o = c_lds + 4 * gg;
        o[0] =  __cosf(A) * c;   o[1] = -__sinf(A) * c;
        o[2] =  __cosf(Bb) * sv; o[3] = -__sinf(Bb) * sv;
    }
    __builtin_amdgcn_wave_barrier();

    // ---------------- encoder MLP, split across the 8 lanes ----------------
    float cqA[8], sqA[8], cqB[8], sqB[8];
    {
        float w1[16];
#pragma unroll
        for (int i = 0; i < 16; i++) w1[i] = ew1[g * 16 + i];
        float aA = eb1[g], aB = aA;
#pragma unroll
        for (int i = 0; i < 16; i++) {
            aA = fmaf(w1[i], xvA[i], aA);
            aB = fmaf(w1[i], xvB[i], aB);
        }
        hx[grp][g]     = fmaxf(aA, 0.0f);
        hx[grp + 8][g] = fmaxf(aB, 0.0f);
        __builtin_amdgcn_wave_barrier();
        float4 hA01 = *(const float4*)&hx[grp][0];
        float4 hA23 = *(const float4*)&hx[grp][4];
        float4 hB01 = *(const float4*)&hx[grp + 8][0];
        float4 hB23 = *(const float4*)&hx[grp + 8][4];
        float w2[8];
#pragma unroll
        for (int i = 0; i < 8; i++) w2[i] = ew2[g * 8 + i];
        float bA = eb2[g], bB = bA;
        bA = fmaf(w2[0], hA01.x, bA); bB = fmaf(w2[0], hB01.x, bB);
        bA = fmaf(w2[1], hA01.y, bA); bB = fmaf(w2[1], hB01.y, bB);
        bA = fmaf(w2[2], hA01.z, bA); bB = fmaf(w2[2], hB01.z, bB);
        bA = fmaf(w2[3], hA01.w, bA); bB = fmaf(w2[3], hB01.w, bB);
        bA = fmaf(w2[4], hA23.x, bA); bB = fmaf(w2[4], hB23.x, bB);
        bA = fmaf(w2[5], hA23.y, bA); bB = fmaf(w2[5], hB23.y, bB);
        bA = fmaf(w2[6], hA23.z, bA); bB = fmaf(w2[6], hB23.z, bB);
        bA = fmaf(w2[7], hA23.w, bA); bB = fmaf(w2[7], hB23.w, bB);
        float eA = 1.0f - __fdividef(2.0f, __expf(2.0f * bA) + 1.0f);  // tanh
        float eB = 1.0f - __fdividef(2.0f, __expf(2.0f * bB) + 1.0f);
        float angA = eA * (0.5f * PI_F), angB = eB * (0.5f * PI_F);
        *(float2*)&csx[grp][2 * g]     = make_float2(__cosf(angA), __sinf(angA));
        *(float2*)&csx[grp + 8][2 * g] = make_float2(__cosf(angB), __sinf(angB));
        __builtin_amdgcn_wave_barrier();
#pragma unroll
        for (int k = 0; k < 4; k++) {
            float4 a = *(const float4*)&csx[grp][4 * k];
            float4 b = *(const float4*)&csx[grp + 8][4 * k];
            cqA[2*k] = a.x; sqA[2*k] = a.y; cqA[2*k+1] = a.z; sqA[2*k+1] = a.w;
            cqB[2*k] = b.x; sqB[2*k] = b.y; cqB[2*k+1] = b.z; sqB[2*k+1] = b.w;
        }
    }

    // ---- per-lane sign masks for cross wires q=0..2 (logical bit 2-q of g)
    int hiM[3], loM[3];
#pragma unroll
    for (int q = 0; q < 3; q++) {
        int hi = (g >> (2 - q)) & 1;
        hiM[q] = hi << 31;                 // flips ai when hi lane
        loM[q] = hiM[q] ^ 0x80000000;      // flips br when lo lane
    }

    // ---- CZ lane scalars (shared by A and B: depend only on g)
    const int g0b = g & 1, g1b = (g >> 1) & 1, g2b = (g >> 2) & 1;
    const float mLo = ((g2b & g1b) ^ (g1b & g0b)) ? -1.0f : 1.0f;  // t < 16
    const float mHi = g0b ? -mLo : mLo;                            // t >= 16

    // ---------------- layer 0: product state, CZ folded --------------------
    v2f zA[32], zB[32];
    {
        float4 cL[8];
#pragma unroll
        for (int q = 0; q < 8; q++) cL[q] = *(const float4*)(c_lds + 4 * q);

        C2 PA; PA.re = 1.0f; PA.im = 0.0f;
        C2 PB = PA;
        C2 AA[5], BcA[5], AB[5], BcB[5];
#pragma unroll
        for (int q = 0; q < 8; q++) {
            float ar, ai, br, bi;
            make_G2(cL[q], cqA[q], sqA[q], ar, ai, br, bi);
            float arB_, aiB_, brB_, biB_;
            make_G2(cL[q], cqB[q], sqB[q], arB_, aiB_, brB_, biB_);
            if (q < 3) {
                const bool hi = (g >> (2 - q)) & 1;
                C2 fA; fA.re = hi ? br : ar;   fA.im = hi ? bi : ai;
                C2 fB; fB.re = hi ? brB_ : arB_; fB.im = hi ? biB_ : aiB_;
                PA = cmul(PA, fA);
                PB = cmul(PB, fB);
            } else {
                AA[q-3].re = ar;    AA[q-3].im = ai;
                BcA[q-3].re = br;   BcA[q-3].im = bi;
                AB[q-3].re = arB_;  AB[q-3].im = aiB_;
                BcB[q-3].re = brB_; BcB[q-3].im = biB_;
            }
        }
        zA[0] = (v2f){PA.re, PA.im};
        zB[0] = (v2f){PB.re, PB.im};
#pragma unroll
        for (int w = 0; w < 5; w++) {
            const int n = 1 << w;
#pragma unroll
            for (int i = n - 1; i >= 0; i--) {
                v2f vA = zA[i], vB = zB[i];
                zA[2*i+1] = cmulv(vA, BcA[w]);
                zA[2*i]   = cmulv(vA, AA[w]);
                zB[2*i+1] = cmulv(vB, BcB[w]);
                zB[2*i]   = cmulv(vB, AB[w]);
            }
        }
#pragma unroll
        for (int t = 0; t < 32; t++) {
            const float m = (t < 16) ? mLo : mHi;
            zA[t] = czt5(t) ? pk_mul_neg_s(m, zA[t]) : pk_mul_s(m, zA[t]);
            zB[t] = czt5(t) ? pk_mul_neg_s(m, zB[t]) : pk_mul_s(m, zB[t]);
        }
    }

    // ---------------- layers 1..NL-1 ---------------------------------------
    for (int l = 1; l < NL; l++) {
        const int gb = l * 8;
        // whole layer's coeffs hoisted: 8 ds_read_b128 issued together,
        // lgkm latency amortized once per layer (affordable under the
        // relaxed VGPR budget)
        float4 cL[8];
#pragma unroll
        for (int q = 0; q < 8; q++) cL[q] = *(const float4*)(c_lds + 4 * (gb + q));

        float ar, ai, br, bi, arB_, aiB_, brB_, biB_;

        make_G2(cL[0], cqA[0], sqA[0], ar, ai, br, bi);
        make_G2(cL[0], cqB[0], sqB[0], arB_, aiB_, brB_, biB_);
        su2_cross2<8>(ar, fxor(ai,hiM[0]), fxor(br,loM[0]), bi,
                      arB_, fxor(aiB_,hiM[0]), fxor(brB_,loM[0]), biB_, zA, zB);

        make_G2(cL[1], cqA[1], sqA[1], ar, ai, br, bi);
        make_G2(cL[1], cqB[1], sqB[1], arB_, aiB_, brB_, biB_);
        su2_cross2<2>(ar, fxor(ai,hiM[1]), fxor(br,loM[1]), bi,
                      arB_, fxor(aiB_,hiM[1]), fxor(brB_,loM[1]), biB_, zA, zB);

        make_G2(cL[2], cqA[2], sqA[2], ar, ai, br, bi);
        make_G2(cL[2], cqB[2], sqB[2], arB_, aiB_, brB_, biB_);
        su2_cross2<1>(ar, fxor(ai,hiM[2]), fxor(br,loM[2]), bi,
                      arB_, fxor(aiB_,hiM[2]), fxor(brB_,loM[2]), biB_, zA, zB);

        make_G2(cL[3], cqA[3], sqA[3], ar, ai, br, bi);
        make_G2(cL[3], cqB[3], sqB[3], arB_, aiB_, brB_, biB_);
        su2_inlane2<16>(ar, ai, br, bi, arB_, aiB_, brB_, biB_, zA, zB);

        make_G2(cL[4], cqA[4], sqA[4], ar, ai, br, bi);
        make_G2(cL[4], cqB[4], sqB[4], arB_, aiB_, brB_, biB_);
        su2_inlane2<8>(ar, ai, br, bi, arB_, aiB_, brB_, biB_, zA, zB);

        make_G2(cL[5], cqA[5], sqA[5], ar, ai, br, bi);
        make_G2(cL[5], cqB[5], sqB[5], arB_, aiB_, brB_, biB_);
        su2_inlane2<4>(ar, ai, br, bi, arB_, aiB_, brB_, biB_, zA, zB);

        make_G2(cL[6], cqA[6], sqA[6], ar, ai, br, bi);
        make_G2(cL[6], cqB[6], sqB[6], arB_, aiB_, brB_, biB_);
        su2_inlane2<2>(ar, ai, br, bi, arB_, aiB_, brB_, biB_, zA, zB);

        make_G2(cL[7], cqA[7], sqA[7], ar, ai, br, bi);
        make_G2(cL[7], cqB[7], sqB[7], arB_, aiB_, brB_, biB_);
        su2_inlane2<1>(ar, ai, br, bi, arB_, aiB_, brB_, biB_, zA, zB);

        // CZ diagonal, both samples
#pragma unroll
        for (int t = 0; t < 32; t++) {
            const float m = (t < 16) ? mLo : mHi;
            zA[t] = czt5(t) ? pk_mul_neg_s(m, zA[t]) : pk_mul_s(m, zA[t]);
            zB[t] = czt5(t) ? pk_mul_neg_s(m, zB[t]) : pk_mul_s(m, zB[t]);
        }
    }

    // ---------------- readout: rotated observables --------------------------
    // <Z_w>_final = cosT_w*<Z_w> - sinT_w*<X_w>; cosT = cq^2-sq^2,
    // sinT = 2*cq*sq. In-lane correlators count each pair once per lane
    // (coeff 2*sinT); cross correlators once per lane-pair side (coeff sinT).
    v2f xaA[8], xaB[8];
    xaA[0] = xcorr_cross<8>(zA);  xaB[0] = xcorr_cross<8>(zB);
    xaA[1] = xcorr_cross<2>(zA);  xaB[1] = xcorr_cross<2>(zB);
    xaA[2] = xcorr_cross<1>(zA);  xaB[2] = xcorr_cross<1>(zB);
    xaA[3] = xcorr_inlane<16>(zA); xaB[3] = xcorr_inlane<16>(zB);
    xaA[4] = xcorr_inlane<8>(zA);  xaB[4] = xcorr_inlane<8>(zB);
    xaA[5] = xcorr_inlane<4>(zA);  xaB[5] = xcorr_inlane<4>(zB);
    xaA[6] = xcorr_inlane<2>(zA);  xaB[6] = xcorr_inlane<2>(zB);
    xaA[7] = xcorr_inlane<1>(zA);  xaB[7] = xcorr_inlane<1>(zB);

    float zWA[8], zWB[8];
    z_readout(zA, g0b, g1b, g2b, zWA);
    z_readout(zB, g0b, g1b, g2b, zWB);

#pragma unroll
    for (int w = 0; w < 8; w++) {
        const float fac = (w < 3 ? 2.0f : 4.0f);
        const float c2A = fmaf(cqA[w], cqA[w], -sqA[w] * sqA[w]);
        const float s2A = fac * (cqA[w] * sqA[w]);
        zWA[w] = fmaf(c2A, zWA[w], -s2A * (xaA[w].x + xaA[w].y));
        const float c2B = fmaf(cqB[w], cqB[w], -sqB[w] * sqB[w]);
        const float s2B = fac * (cqB[w] * sqB[w]);
        zWB[w] = fmaf(c2B, zWB[w], -s2B * (xaB[w].x + xaB[w].y));
    }

    // all-reduce across the 8 lanes of each group (bits 0,1,3 -> all DPP)
#pragma unroll
    for (int w = 0; w < 8; w++) { zWA[w] += lxor<1>(zWA[w]); zWB[w] += lxor<1>(zWB[w]); }
#pragma unroll
    for (int w = 0; w < 8; w++) { zWA[w] += lxor<2>(zWA[w]); zWB[w] += lxor<2>(zWB[w]); }
#pragma unroll
    for (int w = 0; w < 8; w++) { zWA[w] += lxor<8>(zWA[w]); zWB[w] += lxor<8>(zWB[w]); }

    // ---------------- decoder MLP, split across lanes ----------------------
    {
        float d1[8];
#pragma unroll
        for (int w = 0; w < 8; w++) d1[w] = dw1[g * 8 + w];
        float aA = db1[g], aB = aA;
#pragma unroll
        for (int w = 0; w < 8; w++) {
            aA = fmaf(d1[w], zWA[w], aA);
            aB = fmaf(d1[w], zWB[w], aB);
        }
        hx[grp][g]     = fmaxf(aA, 0.0f);
        hx[grp + 8][g] = fmaxf(aB, 0.0f);
        __builtin_amdgcn_wave_barrier();
        float4 hA01 = *(const float4*)&hx[grp][0];
        float4 hA23 = *(const float4*)&hx[grp][4];
        float4 hB01 = *(const float4*)&hx[grp + 8][0];
        float4 hB23 = *(const float4*)&hx[grp + 8][4];
        const int o = g & 3;   // lanes g and g+4 compute identical output o
        float d2[8];
#pragma unroll
        for (int i = 0; i < 8; i++) d2[i] = dw2[o * 8 + i];
        float accA = db2[o], accB = accA;
        accA = fmaf(d2[0], hA01.x, accA); accB = fmaf(d2[0], hB01.x, accB);
        accA = fmaf(d2[1], hA01.y, accA); accB = fmaf(d2[1], hB01.y, accB);
        accA = fmaf(d2[2], hA01.z, accA); accB = fmaf(d2[2], hB01.z, accB);
        accA = fmaf(d2[3], hA01.w, accA); accB = fmaf(d2[3], hB01.w, accB);
        accA = fmaf(d2[4], hA23.x, accA); accB = fmaf(d2[4], hB23.x, accB);
        accA = fmaf(d2[5], hA23.y, accA); accB = fmaf(d2[5], hB23.y, accB);
        accA = fmaf(d2[6], hA23.z, accA); accB = fmaf(d2[6], hB23.z, accB);
        accA = fmaf(d2[7], hA23.w, accA); accB = fmaf(d2[7], hB23.w, accB);
        out[sA * 4 + o] = accA;
        out[sB * 4 + o] = accB;
    }
}

extern "C" void kernel_launch(void* const* d_in, const int* in_sizes, int n_in,
                              void* d_out, int out_size, void* d_ws, size_t ws_size,
                              hipStream_t stream) {
    const float* x   = (const float*)d_in[0];
    const float* ew1 = (const float*)d_in[1];
    const float* eb1 = (const float*)d_in[2];
    const float* ew2 = (const float*)d_in[3];
    const float* eb2 = (const float*)d_in[4];
    const float* qw  = (const float*)d_in[5];
    const float* dw1 = (const float*)d_in[6];
    const float* db1 = (const float*)d_in[7];
    const float* dw2 = (const float*)d_in[8];
    const float* db2 = (const float*)d_in[9];
    float* out = (float*)d_out;

    int B = in_sizes[0] / 16;        // 32768
    int n_gates = in_sizes[5] / 3;   // 32
    int NL = n_gates / 8;            // 4

    // 16 samples per 64-thread block (1 wave; 2 samples per 8-lane group)
    int blocks = (B + 15) / 16;
    qdqn_kernel<<<blocks, 64, 0, stream>>>(x, ew1, eb1, ew2, eb2, qw,
                                           dw1, db1, dw2, db2, out, B, NL);
}

// Round 5
// 114.622 us; speedup vs baseline: 1.0486x; 1.0486x over previous
//
#include <hip/hip_runtime.h>
#include <math.h>

// ---------------------------------------------------------------------------
// HybridQuantumDQN: encoder MLP -> 8-qubit statevector sim -> decoder MLP.
// R15: exact revert to R13 (measured best: 54.9us dispatch / 116.16 harness).
//      R14's amdgpu_waves_per_eu(1,2) was a residency CAP (occupancy 16->10%,
//      +7us); allocator used only 132/256 VGPRs, exonerating register
//      pressure. Keep the R13 schedule (VGPR=128, 2 samples/group).
// R13: TWO samples per 8-lane group (ILP doubling). zA[32]+zB[32] v2f state,
//      every gate applied to A and B interleaved. Weight rows loaded once.
//      2048 blocks x 64 thr.
// R12: 1-wave blocks, no __syncthreads (wave_barrier ordering only).
// R11: final RY layer removed — observables rotated: out_w = cosT*<Z_w> -
//      sinT*<X_w>; <X_w> via packed-fma correlators. Scalar-coeff VOP3P
//      broadcast via op_sel_hi[0]=0 (no v_mov).
// Base (R7): 8 lanes/sample on lane bits {0,1,3} -> cross-wire exchanges all
// DPP (xor1/xor2 = quad_perm, xor8 = row_ror:8). amp = (G<<5)|t. Wires 0..2
// cross, 3..7 in-lane. Layer 0 = product state. CZ = closed-form diagonal.
//
// Session conclusions (measured): VALU-pipe plateau. ~55us kernel flat across
// -8% inst (R11), TLP restructure (R12), ILP x2 (R13); occupancy cap hurts
// (R14). VALUBusy ~70%, HBM 0.4%, 0 LDS conflicts, pk count at algebraic
// minimum. No fp32 MFMA on CDNA4; bf16 MFMA reformulation measured slower
// and breaks the absmax budget. This is the practical ceiling.
// ---------------------------------------------------------------------------

#define PI_F 3.14159265358979323846f

typedef float v2f __attribute__((ext_vector_type(2)));

struct C2 { float re, im; };
__device__ __forceinline__ C2 cmul(C2 a, C2 b) {
    C2 r;
    r.re = fmaf(a.re, b.re, -a.im * b.im);
    r.im = fmaf(a.re, b.im,  a.im * b.re);
    return r;
}
__device__ __forceinline__ float fxor(float x, int m) {
    return __int_as_float(__float_as_int(x) ^ m);
}

// ---------------- packed fp32 primitives (VOP3P) ----------------
__device__ __forceinline__ v2f pk_fma(v2f a, v2f b, v2f c) {
    v2f d; asm("v_pk_fma_f32 %0, %1, %2, %3" : "=v"(d) : "v"(a), "v"(b), "v"(c)); return d;
}

// scalar-coefficient variants: coefficient lives in word0 of its VGPR pair;
// op_sel_hi[0]=0 makes BOTH result halves read word0 (free HW broadcast).
__device__ __forceinline__ v2f mkbc(float c) { v2f r; r.x = c; return r; }

__device__ __forceinline__ v2f pk_mul_s(float c, v2f z) {
    v2f cb = mkbc(c), d;
    asm("v_pk_mul_f32 %0, %1, %2 op_sel_hi:[0,1]"
        : "=v"(d) : "v"(cb), "v"(z));
    return d;
}
__device__ __forceinline__ v2f pk_mul_neg_s(float c, v2f z) {
    v2f cb = mkbc(c), d;
    asm("v_pk_mul_f32 %0, %1, %2 op_sel_hi:[0,1] neg_lo:[1,0] neg_hi:[1,0]"
        : "=v"(d) : "v"(cb), "v"(z));
    return d;
}
__device__ __forceinline__ v2f pk_fma_s(float c, v2f b, v2f acc) {
    v2f cb = mkbc(c), d;
    asm("v_pk_fma_f32 %0, %1, %2, %3 op_sel_hi:[0,1,1]"
        : "=v"(d) : "v"(cb), "v"(b), "v"(acc));
    return d;
}
// d = -(c*b) + acc
__device__ __forceinline__ v2f pk_fma_nn_s(float c, v2f b, v2f acc) {
    v2f cb = mkbc(c), d;
    asm("v_pk_fma_f32 %0, %1, %2, %3 op_sel_hi:[0,1,1] neg_lo:[1,0,0] neg_hi:[1,0,0]"
        : "=v"(d) : "v"(cb), "v"(b), "v"(acc));
    return d;
}
// d.lo = -c*z.hi + acc.lo ; d.hi = c*z.lo + acc.hi   (complex cross term)
__device__ __forceinline__ v2f pk_fma_swl_s(float c, v2f z, v2f acc) {
    v2f cb = mkbc(c), d;
    asm("v_pk_fma_f32 %0, %1, %2, %3 op_sel:[0,1,0] op_sel_hi:[0,0,1] neg_lo:[1,0,0]"
        : "=v"(d) : "v"(cb), "v"(z), "v"(acc));
    return d;
}
// d.lo = c*z.hi + acc.lo ; d.hi = -c*z.lo + acc.hi
__device__ __forceinline__ v2f pk_fma_swh_s(float c, v2f z, v2f acc) {
    v2f cb = mkbc(c), d;
    asm("v_pk_fma_f32 %0, %1, %2, %3 op_sel:[0,1,0] op_sel_hi:[0,0,1] neg_hi:[1,0,0]"
        : "=v"(d) : "v"(cb), "v"(z), "v"(acc));
    return d;
}
// z * (re + i*im), complex scalar coefficient
__device__ __forceinline__ v2f cmulv(v2f z, C2 c) {
    return pk_fma_swl_s(c.im, z, pk_mul_s(c.re, z));
}

// ---------------- cross-lane exchange (all DPP) ----------------
template<int CTRL>
__device__ __forceinline__ float dppf(float x) {
    int xi = __float_as_int(x);
    int r = __builtin_amdgcn_update_dpp(xi, xi, CTRL, 0xF, 0xF, false);
    return __int_as_float(r);
}
template<int M>
__device__ __forceinline__ float lxor(float x) {
    if constexpr (M == 1)      return dppf<0xB1>(x);   // quad_perm [1,0,3,2]
    else if constexpr (M == 2) return dppf<0x4E>(x);   // quad_perm [2,3,0,1]
    else                       return dppf<0x128>(x);  // row_ror:8 == lane^8 in row16
}

// ---------------- gates ----------------
// fused SU(2) gate G = Rot * RY: columns (a,b); G = [[a,-conj(b)],[b,conj(a)]]
__device__ __forceinline__ void load_G2(const float* __restrict__ c_lds, int g,
                                        float cc, float ss,
                                        float& ar, float& ai, float& br, float& bi) {
    const float4 c0 = *(const float4*)(c_lds + 4 * g);  // aR.re aR.im bR.re bR.im
    ar = fmaf(c0.x, cc, -c0.z * ss);
    ai = fmaf(c0.y, cc,  c0.w * ss);
    br = fmaf(c0.z, cc,  c0.x * ss);
    bi = fmaf(c0.w, cc, -c0.y * ss);
}

// cross-lane SU(2) on BOTH samples, chunk-interleaved: gather A, gather B
// (32 DPP), then 32 pk for A and 32 pk for B — B fills A's latency.
template<int M>
__device__ __forceinline__ void su2_cross2(
        float cSrA, float cSiA, float cOrA, float cOiA,
        float cSrB, float cSiB, float cOrB, float cOiB,
        v2f zA[32], v2f zB[32]) {
#pragma unroll
    for (int c = 0; c < 4; c++) {
        v2f pA[8], pB[8];
#pragma unroll
        for (int k = 0; k < 8; k++) {
            pA[k].x = lxor<M>(zA[c * 8 + k].x);
            pA[k].y = lxor<M>(zA[c * 8 + k].y);
        }
#pragma unroll
        for (int k = 0; k < 8; k++) {
            pB[k].x = lxor<M>(zB[c * 8 + k].x);
            pB[k].y = lxor<M>(zB[c * 8 + k].y);
        }
#pragma unroll
        for (int k = 0; k < 8; k++) {
            const int t = c * 8 + k;
            v2f n = pk_mul_s(cSrA, zA[t]);
            n = pk_fma_swl_s(cSiA, zA[t], n);
            n = pk_fma_s    (cOrA, pA[k], n);
            n = pk_fma_swl_s(cOiA, pA[k], n);
            zA[t] = n;
            v2f m = pk_mul_s(cSrB, zB[t]);
            m = pk_fma_swl_s(cSiB, zB[t], m);
            m = pk_fma_s    (cOrB, pB[k], m);
            m = pk_fma_swl_s(cOiB, pB[k], m);
            zB[t] = m;
        }
    }
}

// in-lane SU(2) on reg-index bit ST, both samples per iteration
template<int ST>
__device__ __forceinline__ void su2_inlane2(
        float arA, float aiA, float brA, float biA,
        float arB, float aiB, float brB, float biB,
        v2f zA[32], v2f zB[32]) {
#pragma unroll
    for (int t = 0; t < 32; t++) {
        if ((t & ST) == 0) {
            const int u = t + ST;
            {
                v2f x = zA[t], y = zA[u];
                v2f nx = pk_mul_s(arA, x);
                nx = pk_fma_swl_s(aiA, x, nx);
                nx = pk_fma_nn_s (brA, y, nx);
                nx = pk_fma_swl_s(biA, y, nx);
                v2f ny = pk_mul_s(brA, x);
                ny = pk_fma_swl_s(biA, x, ny);
                ny = pk_fma_s    (arA, y, ny);
                ny = pk_fma_swh_s(aiA, y, ny);
                zA[t] = nx; zA[u] = ny;
            }
            {
                v2f x = zB[t], y = zB[u];
                v2f nx = pk_mul_s(arB, x);
                nx = pk_fma_swl_s(aiB, x, nx);
                nx = pk_fma_nn_s (brB, y, nx);
                nx = pk_fma_swl_s(biB, y, nx);
                v2f ny = pk_mul_s(brB, x);
                ny = pk_fma_swl_s(biB, x, ny);
                ny = pk_fma_s    (arB, y, ny);
                ny = pk_fma_swh_s(aiB, y, ny);
                zB[t] = nx; zB[u] = ny;
            }
        }
    }
}

// ---------------- X correlators: <X_w> = sum_k Re(conj(z_k) z_{k^w}) --------
template<int M>
__device__ __forceinline__ v2f xcorr_cross(const v2f z[32]) {
    v2f acc = (v2f){0.0f, 0.0f};
#pragma unroll
    for (int c = 0; c < 4; c++) {
        v2f p[8];
#pragma unroll
        for (int k = 0; k < 8; k++) {
            p[k].x = lxor<M>(z[c * 8 + k].x);
            p[k].y = lxor<M>(z[c * 8 + k].y);
        }
#pragma unroll
        for (int k = 0; k < 8; k++) acc = pk_fma(z[c * 8 + k], p[k], acc);
    }
    return acc;
}
template<int ST>
__device__ __forceinline__ v2f xcorr_inlane(const v2f z[32]) {
    v2f acc = (v2f){0.0f, 0.0f};
#pragma unroll
    for (int t = 0; t < 32; t++)
        if ((t & ST) == 0) acc = pk_fma(z[t], z[t + ST], acc);
    return acc;
}

// CZ t-part (5-bit): parity of adjacent-bit ANDs
__host__ __device__ constexpr bool czt5(int t) {
    return ((((t >> 4) & (t >> 3)) ^ ((t >> 3) & (t >> 2)) ^
             ((t >> 2) & (t >> 1)) ^ ((t >> 1) & t)) & 1) != 0;
}

// Z-readout tree: probs -> zW[8] partials for one sample
__device__ __forceinline__ void z_readout(const v2f z[32], int g0b, int g1b, int g2b,
                                          float zW[8]) {
    float p[32];
#pragma unroll
    for (int t = 0; t < 32; t++) p[t] = fmaf(z[t].x, z[t].x, z[t].y * z[t].y);
    float s16[16];
    float d = 0.0f;
#pragma unroll
    for (int i = 0; i < 16; i++) {
        s16[i] = p[2*i] + p[2*i+1];
        d += p[2*i] - p[2*i+1];
    }
    zW[7] = d;
    float s8[8]; d = 0.0f;
#pragma unroll
    for (int i = 0; i < 8; i++) {
        s8[i] = s16[2*i] + s16[2*i+1];
        d += s16[2*i] - s16[2*i+1];
    }
    zW[6] = d;
    float s4[4]; d = 0.0f;
#pragma unroll
    for (int i = 0; i < 4; i++) {
        s4[i] = s8[2*i] + s8[2*i+1];
        d += s8[2*i] - s8[2*i+1];
    }
    zW[5] = d;
    float s2a = s4[0] + s4[1], s2b = s4[2] + s4[3];
    zW[4] = (s4[0] - s4[1]) + (s4[2] - s4[3]);
    float sumP = s2a + s2b;
    zW[3] = s2a - s2b;
    zW[0] = g2b ? -sumP : sumP;
    zW[1] = g1b ? -sumP : sumP;
    zW[2] = g0b ? -sumP : sumP;
}

__global__ __launch_bounds__(64, 1) void qdqn_kernel(
    const float* __restrict__ x,
    const float* __restrict__ ew1, const float* __restrict__ eb1,
    const float* __restrict__ ew2, const float* __restrict__ eb2,
    const float* __restrict__ qw,
    const float* __restrict__ dw1, const float* __restrict__ db1,
    const float* __restrict__ dw2, const float* __restrict__ db2,
    float* __restrict__ out, int B, int NL) {
    // one wave per block; all LDS exchange is wave-internal (in-order LDS),
    // ordered with wave_barrier only.
    __shared__ __align__(16) float c_lds[32 * 4];
    __shared__ __align__(16) float hx[16][8];     // h / h2 exchange (A:0-7 B:8-15)
    __shared__ __align__(16) float csx[16][16];   // (c,s) exchange

    const int lane = threadIdx.x;   // blockDim.x == 64
    // sample lane bits {0,1,3}; group id bits {2,4,5} -> all-DPP cross wires
    const int g = (lane & 3) | ((lane >> 1) & 4);          // amp bits 7..5
    const int grp = ((lane >> 2) & 1) | ((lane >> 3) & 6); // group in wave
    int sA = blockIdx.x * 16 + grp;
    int sB = sA + 8;
    if (sA >= B) sA = B - 1;
    if (sB >= B) sB = B - 1;

    // ---- prefetch x for both samples early ----
    float xvA[16], xvB[16];
    {
        const float4* xpA = (const float4*)(x + sA * 16);
        const float4* xpB = (const float4*)(x + sB * 16);
#pragma unroll
        for (int i = 0; i < 4; i++) {
            float4 a = xpA[i], b = xpB[i];
            xvA[4*i] = a.x; xvA[4*i+1] = a.y; xvA[4*i+2] = a.z; xvA[4*i+3] = a.w;
            xvB[4*i] = b.x; xvB[4*i+1] = b.y; xvB[4*i+2] = b.z; xvB[4*i+3] = b.w;
        }
    }

    // ---- Rot SU(2) coeffs once per wave: a = e^{-iA}c, b = e^{-iB}s ----
    const int n_gates = NL * 8;   // 32 <= 64
    if (lane < n_gates) {
        const int gg = lane;
        float phi = qw[3 * gg + 0], th = qw[3 * gg + 1], om = qw[3 * gg + 2];
        float c = __cosf(0.5f * th), sv = __sinf(0.5f * th);
        float A = 0.5f * (phi + om), Bb = 0.5f * (phi - om);
        float* o = c_lds + 4 * gg;
        o[0] =  __cosf(A) * c;   o[1] = -__sinf(A) * c;
        o[2] =  __cosf(Bb) * sv; o[3] = -__sinf(Bb) * sv;
    }
    __builtin_amdgcn_wave_barrier();

    // ---------------- encoder MLP, split across the 8 lanes ----------------
    float cqA[8], sqA[8], cqB[8], sqB[8];
    {
        float w1[16];
#pragma unroll
        for (int i = 0; i < 16; i++) w1[i] = ew1[g * 16 + i];
        float aA = eb1[g], aB = aA;
#pragma unroll
        for (int i = 0; i < 16; i++) {
            aA = fmaf(w1[i], xvA[i], aA);
            aB = fmaf(w1[i], xvB[i], aB);
        }
        hx[grp][g]     = fmaxf(aA, 0.0f);
        hx[grp + 8][g] = fmaxf(aB, 0.0f);
        __builtin_amdgcn_wave_barrier();
        float4 hA01 = *(const float4*)&hx[grp][0];
        float4 hA23 = *(const float4*)&hx[grp][4];
        float4 hB01 = *(const float4*)&hx[grp + 8][0];
        float4 hB23 = *(const float4*)&hx[grp + 8][4];
        float w2[8];
#pragma unroll
        for (int i = 0; i < 8; i++) w2[i] = ew2[g * 8 + i];
        float bA = eb2[g], bB = bA;
        bA = fmaf(w2[0], hA01.x, bA); bB = fmaf(w2[0], hB01.x, bB);
        bA = fmaf(w2[1], hA01.y, bA); bB = fmaf(w2[1], hB01.y, bB);
        bA = fmaf(w2[2], hA01.z, bA); bB = fmaf(w2[2], hB01.z, bB);
        bA = fmaf(w2[3], hA01.w, bA); bB = fmaf(w2[3], hB01.w, bB);
        bA = fmaf(w2[4], hA23.x, bA); bB = fmaf(w2[4], hB23.x, bB);
        bA = fmaf(w2[5], hA23.y, bA); bB = fmaf(w2[5], hB23.y, bB);
        bA = fmaf(w2[6], hA23.z, bA); bB = fmaf(w2[6], hB23.z, bB);
        bA = fmaf(w2[7], hA23.w, bA); bB = fmaf(w2[7], hB23.w, bB);
        float eA = 1.0f - __fdividef(2.0f, __expf(2.0f * bA) + 1.0f);  // tanh
        float eB = 1.0f - __fdividef(2.0f, __expf(2.0f * bB) + 1.0f);
        float angA = eA * (0.5f * PI_F), angB = eB * (0.5f * PI_F);
        *(float2*)&csx[grp][2 * g]     = make_float2(__cosf(angA), __sinf(angA));
        *(float2*)&csx[grp + 8][2 * g] = make_float2(__cosf(angB), __sinf(angB));
        __builtin_amdgcn_wave_barrier();
#pragma unroll
        for (int k = 0; k < 4; k++) {
            float4 a = *(const float4*)&csx[grp][4 * k];
            float4 b = *(const float4*)&csx[grp + 8][4 * k];
            cqA[2*k] = a.x; sqA[2*k] = a.y; cqA[2*k+1] = a.z; sqA[2*k+1] = a.w;
            cqB[2*k] = b.x; sqB[2*k] = b.y; cqB[2*k+1] = b.z; sqB[2*k+1] = b.w;
        }
    }

    // ---- per-lane sign masks for cross wires q=0..2 (logical bit 2-q of g)
    int hiM[3], loM[3];
#pragma unroll
    for (int q = 0; q < 3; q++) {
        int hi = (g >> (2 - q)) & 1;
        hiM[q] = hi << 31;                 // flips ai when hi lane
        loM[q] = hiM[q] ^ 0x80000000;      // flips br when lo lane
    }

    // ---- CZ lane scalars (shared by A and B: depend only on g)
    const int g0b = g & 1, g1b = (g >> 1) & 1, g2b = (g >> 2) & 1;
    const float mLo = ((g2b & g1b) ^ (g1b & g0b)) ? -1.0f : 1.0f;  // t < 16
    const float mHi = g0b ? -mLo : mLo;                            // t >= 16

    // ---------------- layer 0: product state, CZ folded --------------------
    v2f zA[32], zB[32];
    {
        C2 PA; PA.re = 1.0f; PA.im = 0.0f;
        C2 PB = PA;
        C2 AA[5], BcA[5], AB[5], BcB[5];
#pragma unroll
        for (int q = 0; q < 8; q++) {
            float ar, ai, br, bi;
            load_G2(c_lds, q, cqA[q], sqA[q], ar, ai, br, bi);
            float arB_, aiB_, brB_, biB_;
            load_G2(c_lds, q, cqB[q], sqB[q], arB_, aiB_, brB_, biB_);
            if (q < 3) {
                const bool hi = (g >> (2 - q)) & 1;
                C2 fA; fA.re = hi ? br : ar;   fA.im = hi ? bi : ai;
                C2 fB; fB.re = hi ? brB_ : arB_; fB.im = hi ? biB_ : aiB_;
                PA = cmul(PA, fA);
                PB = cmul(PB, fB);
            } else {
                AA[q-3].re = ar;    AA[q-3].im = ai;
                BcA[q-3].re = br;   BcA[q-3].im = bi;
                AB[q-3].re = arB_;  AB[q-3].im = aiB_;
                BcB[q-3].re = brB_; BcB[q-3].im = biB_;
            }
        }
        zA[0] = (v2f){PA.re, PA.im};
        zB[0] = (v2f){PB.re, PB.im};
#pragma unroll
        for (int w = 0; w < 5; w++) {
            const int n = 1 << w;
#pragma unroll
            for (int i = n - 1; i >= 0; i--) {
                v2f vA = zA[i], vB = zB[i];
                zA[2*i+1] = cmulv(vA, BcA[w]);
                zA[2*i]   = cmulv(vA, AA[w]);
                zB[2*i+1] = cmulv(vB, BcB[w]);
                zB[2*i]   = cmulv(vB, AB[w]);
            }
        }
#pragma unroll
        for (int t = 0; t < 32; t++) {
            const float m = (t < 16) ? mLo : mHi;
            zA[t] = czt5(t) ? pk_mul_neg_s(m, zA[t]) : pk_mul_s(m, zA[t]);
            zB[t] = czt5(t) ? pk_mul_neg_s(m, zB[t]) : pk_mul_s(m, zB[t]);
        }
    }

    // ---------------- layers 1..NL-1 ---------------------------------------
    for (int l = 1; l < NL; l++) {
        const int gb = l * 8;
        float ar, ai, br, bi, arB_, aiB_, brB_, biB_;

        load_G2(c_lds, gb+0, cqA[0], sqA[0], ar, ai, br, bi);
        load_G2(c_lds, gb+0, cqB[0], sqB[0], arB_, aiB_, brB_, biB_);
        su2_cross2<8>(ar, fxor(ai,hiM[0]), fxor(br,loM[0]), bi,
                      arB_, fxor(aiB_,hiM[0]), fxor(brB_,loM[0]), biB_, zA, zB);

        load_G2(c_lds, gb+1, cqA[1], sqA[1], ar, ai, br, bi);
        load_G2(c_lds, gb+1, cqB[1], sqB[1], arB_, aiB_, brB_, biB_);
        su2_cross2<2>(ar, fxor(ai,hiM[1]), fxor(br,loM[1]), bi,
                      arB_, fxor(aiB_,hiM[1]), fxor(brB_,loM[1]), biB_, zA, zB);

        load_G2(c_lds, gb+2, cqA[2], sqA[2], ar, ai, br, bi);
        load_G2(c_lds, gb+2, cqB[2], sqB[2], arB_, aiB_, brB_, biB_);
        su2_cross2<1>(ar, fxor(ai,hiM[2]), fxor(br,loM[2]), bi,
                      arB_, fxor(aiB_,hiM[2]), fxor(brB_,loM[2]), biB_, zA, zB);

        load_G2(c_lds, gb+3, cqA[3], sqA[3], ar, ai, br, bi);
        load_G2(c_lds, gb+3, cqB[3], sqB[3], arB_, aiB_, brB_, biB_);
        su2_inlane2<16>(ar, ai, br, bi, arB_, aiB_, brB_, biB_, zA, zB);

        load_G2(c_lds, gb+4, cqA[4], sqA[4], ar, ai, br, bi);
        load_G2(c_lds, gb+4, cqB[4], sqB[4], arB_, aiB_, brB_, biB_);
        su2_inlane2<8>(ar, ai, br, bi, arB_, aiB_, brB_, biB_, zA, zB);

        load_G2(c_lds, gb+5, cqA[5], sqA[5], ar, ai, br, bi);
        load_G2(c_lds, gb+5, cqB[5], sqB[5], arB_, aiB_, brB_, biB_);
        su2_inlane2<4>(ar, ai, br, bi, arB_, aiB_, brB_, biB_, zA, zB);

        load_G2(c_lds, gb+6, cqA[6], sqA[6], ar, ai, br, bi);
        load_G2(c_lds, gb+6, cqB[6], sqB[6], arB_, aiB_, brB_, biB_);
        su2_inlane2<2>(ar, ai, br, bi, arB_, aiB_, brB_, biB_, zA, zB);

        load_G2(c_lds, gb+7, cqA[7], sqA[7], ar, ai, br, bi);
        load_G2(c_lds, gb+7, cqB[7], sqB[7], arB_, aiB_, brB_, biB_);
        su2_inlane2<1>(ar, ai, br, bi, arB_, aiB_, brB_, biB_, zA, zB);

        // CZ diagonal, both samples
#pragma unroll
        for (int t = 0; t < 32; t++) {
            const float m = (t < 16) ? mLo : mHi;
            zA[t] = czt5(t) ? pk_mul_neg_s(m, zA[t]) : pk_mul_s(m, zA[t]);
            zB[t] = czt5(t) ? pk_mul_neg_s(m, zB[t]) : pk_mul_s(m, zB[t]);
        }
    }

    // ---------------- readout: rotated observables --------------------------
    // <Z_w>_final = cosT_w*<Z_w> - sinT_w*<X_w>; cosT = cq^2-sq^2,
    // sinT = 2*cq*sq. In-lane correlators count each pair once per lane
    // (coeff 2*sinT); cross correlators once per lane-pair side (coeff sinT).
    v2f xaA[8], xaB[8];
    xaA[0] = xcorr_cross<8>(zA);  xaB[0] = xcorr_cross<8>(zB);
    xaA[1] = xcorr_cross<2>(zA);  xaB[1] = xcorr_cross<2>(zB);
    xaA[2] = xcorr_cross<1>(zA);  xaB[2] = xcorr_cross<1>(zB);
    xaA[3] = xcorr_inlane<16>(zA); xaB[3] = xcorr_inlane<16>(zB);
    xaA[4] = xcorr_inlane<8>(zA);  xaB[4] = xcorr_inlane<8>(zB);
    xaA[5] = xcorr_inlane<4>(zA);  xaB[5] = xcorr_inlane<4>(zB);
    xaA[6] = xcorr_inlane<2>(zA);  xaB[6] = xcorr_inlane<2>(zB);
    xaA[7] = xcorr_inlane<1>(zA);  xaB[7] = xcorr_inlane<1>(zB);

    float zWA[8], zWB[8];
    z_readout(zA, g0b, g1b, g2b, zWA);
    z_readout(zB, g0b, g1b, g2b, zWB);

#pragma unroll
    for (int w = 0; w < 8; w++) {
        const float fac = (w < 3 ? 2.0f : 4.0f);
        const float c2A = fmaf(cqA[w], cqA[w], -sqA[w] * sqA[w]);
        const float s2A = fac * (cqA[w] * sqA[w]);
        zWA[w] = fmaf(c2A, zWA[w], -s2A * (xaA[w].x + xaA[w].y));
        const float c2B = fmaf(cqB[w], cqB[w], -sqB[w] * sqB[w]);
        const float s2B = fac * (cqB[w] * sqB[w]);
        zWB[w] = fmaf(c2B, zWB[w], -s2B * (xaB[w].x + xaB[w].y));
    }

    // all-reduce across the 8 lanes of each group (bits 0,1,3 -> all DPP)
#pragma unroll
    for (int w = 0; w < 8; w++) { zWA[w] += lxor<1>(zWA[w]); zWB[w] += lxor<1>(zWB[w]); }
#pragma unroll
    for (int w = 0; w < 8; w++) { zWA[w] += lxor<2>(zWA[w]); zWB[w] += lxor<2>(zWB[w]); }
#pragma unroll
    for (int w = 0; w < 8; w++) { zWA[w] += lxor<8>(zWA[w]); zWB[w] += lxor<8>(zWB[w]); }

    // ---------------- decoder MLP, split across lanes ----------------------
    {
        float d1[8];
#pragma unroll
        for (int w = 0; w < 8; w++) d1[w] = dw1[g * 8 + w];
        float aA = db1[g], aB = aA;
#pragma unroll
        for (int w = 0; w < 8; w++) {
            aA = fmaf(d1[w], zWA[w], aA);
            aB = fmaf(d1[w], zWB[w], aB);
        }
        hx[grp][g]     = fmaxf(aA, 0.0f);
        hx[grp + 8][g] = fmaxf(aB, 0.0f);
        __builtin_amdgcn_wave_barrier();
        float4 hA01 = *(const float4*)&hx[grp][0];
        float4 hA23 = *(const float4*)&hx[grp][4];
        float4 hB01 = *(const float4*)&hx[grp + 8][0];
        float4 hB23 = *(const float4*)&hx[grp + 8][4];
        const int o = g & 3;   // lanes g and g+4 compute identical output o
        float d2[8];
#pragma unroll
        for (int i = 0; i < 8; i++) d2[i] = dw2[o * 8 + i];
        float accA = db2[o], accB = accA;
        accA = fmaf(d2[0], hA01.x, accA); accB = fmaf(d2[0], hB01.x, accB);
        accA = fmaf(d2[1], hA01.y, accA); accB = fmaf(d2[1], hB01.y, accB);
        accA = fmaf(d2[2], hA01.z, accA); accB = fmaf(d2[2], hB01.z, accB);
        accA = fmaf(d2[3], hA01.w, accA); accB = fmaf(d2[3], hB01.w, accB);
        accA = fmaf(d2[4], hA23.x, accA); accB = fmaf(d2[4], hB23.x, accB);
        accA = fmaf(d2[5], hA23.y, accA); accB = fmaf(d2[5], hB23.y, accB);
        accA = fmaf(d2[6], hA23.z, accA); accB = fmaf(d2[6], hB23.z, accB);
        accA = fmaf(d2[7], hA23.w, accA); accB = fmaf(d2[7], hB23.w, accB);
        out[sA * 4 + o] = accA;
        out[sB * 4 + o] = accB;
    }
}

extern "C" void kernel_launch(void* const* d_in, const int* in_sizes, int n_in,
                              void* d_out, int out_size, void* d_ws, size_t ws_size,
                              hipStream_t stream) {
    const float* x   = (const float*)d_in[0];
    const float* ew1 = (const float*)d_in[1];
    const float* eb1 = (const float*)d_in[2];
    const float* ew2 = (const float*)d_in[3];
    const float* eb2 = (const float*)d_in[4];
    const float* qw  = (const float*)d_in[5];
    const float* dw1 = (const float*)d_in[6];
    const float* db1 = (const float*)d_in[7];
    const float* dw2 = (const float*)d_in[8];
    const float* db2 = (const float*)d_in[9];
    float* out = (float*)d_out;

    int B = in_sizes[0] / 16;        // 32768
    int n_gates = in_sizes[5] / 3;   // 32
    int NL = n_gates / 8;            // 4

    // 16 samples per 64-thread block (1 wave; 2 samples per 8-lane group)
    int blocks = (B + 15) / 16;
    qdqn_kernel<<<blocks, 64, 0, stream>>>(x, ew1, eb1, ew2, eb2, qw,
                                           dw1, db1, dw2, db2, out, B, NL);
}